// Round 11
// baseline (374.296 us; speedup 1.0000x reference)
//
#include <hip/hip_runtime.h>
#include <hip/hip_fp16.h>

// GCN 2-layer via device-built CSR + gather.
// R11: bucketA reworked — per-wave private LDS histograms/cursors (4x less
// same-address atomic serialization), edges register-cached (one global read),
// packed 4B tmp entries ((dlow<<17)|src). bucketB reads packed tmp.

#define N_NODES 100000
#define N_EDGES 1600000
#define BSHIFT 8
#define NBUCK ((N_NODES + 255) / 256)   // 391
#define CAP 5120                         // tmp region/bucket (Poisson 4092 + 16 sigma)
#define CSRCAP 6656                      // csr region/bucket, %16==0
#define EPB 2048
#define NBLKA ((N_EDGES + EPB - 1) / EPB)   // 782

// gfix[b] = b*CAP; zero dummy rows h1s[N]/h2s[N] (ws re-poisoned 0xAA each call)
__global__ __launch_bounds__(256) void k_init(int* gfix, __half* h1s, __half* h2s) {
    int i = blockIdx.x * 256 + threadIdx.x;
    if (i < NBUCK) gfix[i] = i * CAP;
    if (blockIdx.x == 1) {
        int t = threadIdx.x;
        if (t < 32) ((unsigned*)(h1s + (size_t)N_NODES * 64))[t] = 0u;
        else if (t < 48) ((unsigned*)(h2s + (size_t)N_NODES * 32))[t - 32] = 0u;
    }
}

// Pass A: bin packed (dlow,src) into fixed NBUCK regions of tmp.
// Per-wave private lcnt/lpos; edges register-cached; 8 edges/thread.
__global__ __launch_bounds__(256) void k_bucketA(const int* __restrict__ src,
                                                 const int* __restrict__ dst,
                                                 int* gfix, unsigned* __restrict__ tmp) {
    __shared__ int lcnt[4][NBUCK];
    __shared__ int lpos[4][NBUCK];
    int t = threadIdx.x, w = t >> 6, lane = t & 63;
    for (int b = lane; b < NBUCK; b += 64) lcnt[w][b] = 0;
    __syncthreads();
    long e0 = (long)blockIdx.x * EPB;
    int d[8], s[8];
    #pragma unroll
    for (int k = 0; k < 8; ++k) {
        long e = e0 + k * 256 + t;
        bool v = e < N_EDGES;
        d[k] = v ? dst[e] : -1;
        s[k] = v ? src[e] : 0;
        if (v) atomicAdd(&lcnt[w][d[k] >> BSHIFT], 1);
    }
    __syncthreads();
    for (int b = lane; b < NBUCK; b += 64) {
        int c = lcnt[w][b];
        lpos[w][b] = c ? atomicAdd(&gfix[b], c) : 0;
    }
    __syncthreads();
    #pragma unroll
    for (int k = 0; k < 8; ++k) {
        if (d[k] >= 0) {
            int bkt = d[k] >> BSHIFT;
            int p = atomicAdd(&lpos[w][bkt], 1);
            if (p < bkt * CAP + CAP)           // overflow guard (never fires)
                tmp[p] = ((unsigned)(d[k] & 255) << 17) | (unsigned)s[k];
        }
    }
}

// Pass B: one block per bucket (exclusive owner). LDS histogram of its packed
// pairs, local padded (16) exclusive scan -> rowstart/udeg/dinv; LDS-cursor
// scatter into the bucket's fixed csr region; pad tails with dummy N_NODES.
__global__ __launch_bounds__(256) void k_bucketB(const int* __restrict__ gfix,
                                                 const unsigned* __restrict__ tmp,
                                                 int* __restrict__ rowstart,
                                                 int* __restrict__ udeg,
                                                 float* __restrict__ dinv,
                                                 int* __restrict__ csr) {
    __shared__ int cnt[256];
    __shared__ int s[256];
    __shared__ int cur[256];
    __shared__ int rsl[256];
    int b  = blockIdx.x;
    int t  = threadIdx.x;
    int n0 = b << BSHIFT;
    int nn = min(256, N_NODES - n0);
    cnt[t] = 0;
    __syncthreads();
    int start = b * CAP;
    int end   = min(gfix[b], start + CAP);   // gfix[b] = start + bucket pair count
    for (int e = start + t; e < end; e += 256)
        atomicAdd(&cnt[tmp[e] >> 17], 1);
    __syncthreads();
    int c   = (t < nn) ? cnt[t] : 0;
    int pad = (c + 15) & ~15;
    s[t] = pad;
    __syncthreads();
    for (int off = 1; off < 256; off <<= 1) {
        int add = (t >= off) ? s[t - off] : 0;
        __syncthreads();
        s[t] += add;
        __syncthreads();
    }
    int rs = b * CSRCAP + s[t] - pad;        // exclusive scan within bucket
    rsl[t] = rs;
    cur[t] = rs;
    if (t < nn) {
        rowstart[n0 + t] = rs;
        udeg[n0 + t]     = c;
        dinv[n0 + t]     = rsqrtf((float)(c + 1));
    }
    __syncthreads();
    for (int e = start + t; e < end; e += 256) {
        unsigned p = tmp[e];
        int pos = atomicAdd(&cur[p >> 17], 1);
        csr[pos] = (int)(p & 0x1FFFFu);
    }
    __syncthreads();
    int pe = rsl[t] + pad;                   // cur[t] == rsl[t]+c after scatter
    for (int p = cur[t]; p < pe; ++p) csr[p] = N_NODES;
}

// h1s = fp16((x @ W1) * dinv[row])
__global__ __launch_bounds__(256) void k_gemm1(const float* __restrict__ x,
                                               const float* __restrict__ W1,
                                               const float* __restrict__ dinv,
                                               __half* __restrict__ h1s) {
    __shared__ float Ws[128 * 64];      // 32 KB
    __shared__ float xs[16][132];       // +4 pad, conflict-free
    int tid = threadIdx.x;
    for (int i = tid * 4; i < 128 * 64; i += 1024)
        *(float4*)&Ws[i] = *(const float4*)&W1[i];
    long rowBase = (long)blockIdx.x * 16;
    for (int i = tid; i < 512; i += 256) {
        int r = i >> 5, c4 = i & 31;
        *(float4*)&xs[r][c4 * 4] = *(const float4*)&x[(rowBase + r) * 128 + c4 * 4];
    }
    __syncthreads();
    int r  = tid >> 4;
    int cg = (tid & 15) * 4;
    float a0 = 0, a1 = 0, a2 = 0, a3 = 0;
    #pragma unroll
    for (int k = 0; k < 128; ++k) {
        float xv = xs[r][k];
        const float* w = &Ws[k * 64 + cg];
        a0 = fmaf(xv, w[0], a0); a1 = fmaf(xv, w[1], a1);
        a2 = fmaf(xv, w[2], a2); a3 = fmaf(xv, w[3], a3);
    }
    long row = rowBase + r;
    float dv = dinv[row];
    ushort4 pk;
    pk.x = __half_as_ushort(__float2half_rn(a0 * dv));
    pk.y = __half_as_ushort(__float2half_rn(a1 * dv));
    pk.z = __half_as_ushort(__float2half_rn(a2 * dv));
    pk.w = __half_as_ushort(__float2half_rn(a3 * dv));
    *(ushort4*)&h1s[row * 64 + cg] = pk;
}

// Fused layer-1 gather + layer-2 GEMM. Wave per node.
// lane = (pr = c>>4 in {0..3}, hc = c&15 -> channels 4hc..4hc+3).
// 16 neighbors/iter: 4 int4 csr broadcasts + 4 x 8B row loads per lane.
__global__ __launch_bounds__(256) void k_fused1(const int* __restrict__ rowstart,
                                                const int* __restrict__ udeg,
                                                const int* __restrict__ csr,
                                                const float* __restrict__ dinv,
                                                const __half* __restrict__ h1s,
                                                const float* __restrict__ b1,
                                                const float* __restrict__ W2,
                                                __half* __restrict__ h2s) {
    __shared__ float W2s[64 * 32];   // 8 KB
    __shared__ float g1row[4][72];   // per-wave row, padded
    int tid = threadIdx.x;
    for (int idx = tid * 4; idx < 64 * 32; idx += 1024)
        *(float4*)&W2s[idx] = *(const float4*)&W2[idx];
    __syncthreads();                 // covers W2s staging only
    int w = tid >> 6, c = tid & 63;
    int pr = c >> 4, hc = c & 15;
    int i = blockIdx.x * 4 + w;
    int n = udeg[i];
    int base = rowstart[i];
    float4 acc = {0.f, 0.f, 0.f, 0.f};
    if (pr == 0) {
        uint2 v = *(const uint2*)(h1s + (size_t)i * 64 + hc * 4);
        float2 a = __half22float2(*(__half2*)&v.x);
        float2 b = __half22float2(*(__half2*)&v.y);
        acc.x = a.x; acc.y = a.y; acc.z = b.x; acc.w = b.y;
    }
    for (int k = 0; k < n; k += 16) {
        int4 ia = *(const int4*)&csr[base + k];
        int4 ib = *(const int4*)&csr[base + k + 4];
        int4 ic = *(const int4*)&csr[base + k + 8];
        int4 id = *(const int4*)&csr[base + k + 12];
        int s0, s1, s2, s3;
        switch (pr) {
            case 0:  s0 = ia.x; s1 = ib.x; s2 = ic.x; s3 = id.x; break;
            case 1:  s0 = ia.y; s1 = ib.y; s2 = ic.y; s3 = id.y; break;
            case 2:  s0 = ia.z; s1 = ib.z; s2 = ic.z; s3 = id.z; break;
            default: s0 = ia.w; s1 = ib.w; s2 = ic.w; s3 = id.w; break;
        }
        uint2 v0 = *(const uint2*)(h1s + (size_t)s0 * 64 + hc * 4);
        uint2 v1 = *(const uint2*)(h1s + (size_t)s1 * 64 + hc * 4);
        uint2 v2 = *(const uint2*)(h1s + (size_t)s2 * 64 + hc * 4);
        uint2 v3 = *(const uint2*)(h1s + (size_t)s3 * 64 + hc * 4);
        float2 a0 = __half22float2(*(__half2*)&v0.x), b0 = __half22float2(*(__half2*)&v0.y);
        float2 a1 = __half22float2(*(__half2*)&v1.x), b1f = __half22float2(*(__half2*)&v1.y);
        float2 a2 = __half22float2(*(__half2*)&v2.x), b2f = __half22float2(*(__half2*)&v2.y);
        float2 a3 = __half22float2(*(__half2*)&v3.x), b3f = __half22float2(*(__half2*)&v3.y);
        acc.x += (a0.x + a1.x) + (a2.x + a3.x);
        acc.y += (a0.y + a1.y) + (a2.y + a3.y);
        acc.z += (b0.x + b1f.x) + (b2f.x + b3f.x);
        acc.w += (b0.y + b1f.y) + (b2f.y + b3f.y);
    }
    acc.x += __shfl_xor(acc.x, 16); acc.y += __shfl_xor(acc.y, 16);
    acc.z += __shfl_xor(acc.z, 16); acc.w += __shfl_xor(acc.w, 16);
    acc.x += __shfl_xor(acc.x, 32); acc.y += __shfl_xor(acc.y, 32);
    acc.z += __shfl_xor(acc.z, 32); acc.w += __shfl_xor(acc.w, 32);
    float dvi = dinv[i];
    if (pr == 0) {
        float4 bb = *(const float4*)&b1[hc * 4];
        float4 g;
        g.x = fmaxf(fmaf(dvi, acc.x, bb.x), 0.f);
        g.y = fmaxf(fmaf(dvi, acc.y, bb.y), 0.f);
        g.z = fmaxf(fmaf(dvi, acc.z, bb.z), 0.f);
        g.w = fmaxf(fmaf(dvi, acc.w, bb.w), 0.f);
        *(float4*)&g1row[w][hc * 4] = g;
    }
    // wave-private LDS RAW: compiler inserts lgkmcnt wait; no barrier needed
    int j = c & 31, hf = c >> 5;
    float dot = 0.f;
    #pragma unroll
    for (int cc = 0; cc < 32; ++cc)
        dot = fmaf(g1row[w][hf * 32 + cc], W2s[(hf * 32 + cc) * 32 + j], dot);
    dot += __shfl_xor(dot, 32);
    if (hf == 0)
        h2s[(size_t)i * 32 + j] = __float2half_rn(dot * dvi);
}

// out[i] = dinv[i]*(sum_s h2s[s] + h2s[i]) + b2 — wave per node.
// lane = (pr = c>>3 in {0..7}, hc = c&7 -> channels 4hc..4hc+3).
__global__ __launch_bounds__(256) void k_gather2(const int* __restrict__ rowstart,
                                                 const int* __restrict__ udeg,
                                                 const int* __restrict__ csr,
                                                 const float* __restrict__ dinv,
                                                 const __half* __restrict__ h2s,
                                                 const float* __restrict__ b2,
                                                 float* __restrict__ out) {
    int tid = threadIdx.x;
    int w = tid >> 6, c = tid & 63;
    int pr = c >> 3, hc = c & 7;
    int i = blockIdx.x * 4 + w;
    int n = udeg[i];
    int base = rowstart[i];
    float4 acc = {0.f, 0.f, 0.f, 0.f};
    if (pr == 0) {
        uint2 v = *(const uint2*)(h2s + (size_t)i * 32 + hc * 4);
        float2 a = __half22float2(*(__half2*)&v.x);
        float2 b = __half22float2(*(__half2*)&v.y);
        acc.x = a.x; acc.y = a.y; acc.z = b.x; acc.w = b.y;
    }
    for (int k = 0; k < n; k += 16) {
        int4 ia = *(const int4*)&csr[base + k];
        int4 ib = *(const int4*)&csr[base + k + 4];
        int4 ic = *(const int4*)&csr[base + k + 8];
        int4 id = *(const int4*)&csr[base + k + 12];
        int s0, s1;
        switch (pr) {
            case 0:  s0 = ia.x; s1 = ic.x; break;
            case 1:  s0 = ia.y; s1 = ic.y; break;
            case 2:  s0 = ia.z; s1 = ic.z; break;
            case 3:  s0 = ia.w; s1 = ic.w; break;
            case 4:  s0 = ib.x; s1 = id.x; break;
            case 5:  s0 = ib.y; s1 = id.y; break;
            case 6:  s0 = ib.z; s1 = id.z; break;
            default: s0 = ib.w; s1 = id.w; break;
        }
        uint2 v0 = *(const uint2*)(h2s + (size_t)s0 * 32 + hc * 4);
        uint2 v1 = *(const uint2*)(h2s + (size_t)s1 * 32 + hc * 4);
        float2 a0 = __half22float2(*(__half2*)&v0.x), b0 = __half22float2(*(__half2*)&v0.y);
        float2 a1 = __half22float2(*(__half2*)&v1.x), b1f = __half22float2(*(__half2*)&v1.y);
        acc.x += a0.x + a1.x; acc.y += a0.y + a1.y;
        acc.z += b0.x + b1f.x; acc.w += b0.y + b1f.y;
    }
    acc.x += __shfl_xor(acc.x, 8);  acc.y += __shfl_xor(acc.y, 8);
    acc.z += __shfl_xor(acc.z, 8);  acc.w += __shfl_xor(acc.w, 8);
    acc.x += __shfl_xor(acc.x, 16); acc.y += __shfl_xor(acc.y, 16);
    acc.z += __shfl_xor(acc.z, 16); acc.w += __shfl_xor(acc.w, 16);
    acc.x += __shfl_xor(acc.x, 32); acc.y += __shfl_xor(acc.y, 32);
    acc.z += __shfl_xor(acc.z, 32); acc.w += __shfl_xor(acc.w, 32);
    if (pr == 0) {
        float dvi = dinv[i];
        float4 bb = *(const float4*)&b2[hc * 4];
        float4 o;
        o.x = fmaf(dvi, acc.x, bb.x);
        o.y = fmaf(dvi, acc.y, bb.y);
        o.z = fmaf(dvi, acc.z, bb.z);
        o.w = fmaf(dvi, acc.w, bb.w);
        *(float4*)&out[(size_t)i * 32 + hc * 4] = o;
    }
}

extern "C" void kernel_launch(void* const* d_in, const int* in_sizes, int n_in,
                              void* d_out, int out_size, void* d_ws, size_t ws_size,
                              hipStream_t stream) {
    const float* x  = (const float*)d_in[0];
    const int*   ei = (const int*)d_in[1];     // [2][N_EDGES]: row0=src, row1=dst
    const float* W1 = (const float*)d_in[2];
    const float* b1 = (const float*)d_in[3];
    const float* W2 = (const float*)d_in[4];
    const float* b2 = (const float*)d_in[5];
    float* out = (float*)d_out;

    const int* src = ei;
    const int* dst = ei + N_EDGES;

    char* ws = (char*)d_ws;
    const size_t MB = 1u << 20;
    int*      udeg     = (int*)     (ws + 0);                    // 400 KB
    float*    dinv     = (float*)   (ws + 512 * 1024);           // 400 KB
    int*      rowstart = (int*)     (ws + 1 * MB);               // 400 KB
    int*      gfix     = (int*)     (ws + 1 * MB + 512 * 1024);  // 391 ints
    int*      csr      = (int*)     (ws + 2 * MB);               // 391*6656*4 = 10.4 MB
    unsigned* tmp      = (unsigned*)(ws + 13 * MB);              // 391*5120*4 = 8.0 MB
    __half*   h1s      = (__half*)  (ws + 22 * MB);              // (N+1)*128B = 12.8 MB
    __half*   h2s      = (__half*)  (ws + 35 * MB);              // (N+1)*64B  = 6.4 MB (ends ~41.4 MB)

    k_init   <<<2, 256, 0, stream>>>(gfix, h1s, h2s);
    k_bucketA<<<NBLKA, 256, 0, stream>>>(src, dst, gfix, tmp);
    k_bucketB<<<NBUCK, 256, 0, stream>>>(gfix, tmp, rowstart, udeg, dinv, csr);
    k_gemm1  <<<N_NODES / 16, 256, 0, stream>>>(x, W1, dinv, h1s);
    k_fused1 <<<N_NODES / 4, 256, 0, stream>>>(rowstart, udeg, csr, dinv, h1s, b1, W2, h2s);
    k_gather2<<<N_NODES / 4, 256, 0, stream>>>(rowstart, udeg, csr, dinv, h2s, b2, out);
}

// Round 12
// 271.913 us; speedup vs baseline: 1.3765x; 1.3765x over previous
//
#include <hip/hip_runtime.h>
#include <hip/hip_fp16.h>

// GCN 2-layer via device-built CSR + gather.
// R12: bucketA = shared block histogram (ONE gfix reserve pass per block —
// R11's per-wave split 4x'd the contended global atomics and regressed),
// EPB=2048 (halves reserve traffic vs R10), int4 register-cached edge reads,
// packed 4B tmp ((dlow<<17)|src). Rest identical to R10/R11.

#define N_NODES 100000
#define N_EDGES 1600000
#define BSHIFT 8
#define NBUCK ((N_NODES + 255) / 256)   // 391
#define CAP 5120                         // tmp region/bucket (Poisson 4092 + 16 sigma)
#define CSRCAP 6656                      // csr region/bucket, %16==0
#define EPB 2048
#define NBLKA ((N_EDGES + EPB - 1) / EPB)   // 782

// gfix[b] = b*CAP; zero dummy rows h1s[N]/h2s[N] (ws re-poisoned 0xAA each call)
__global__ __launch_bounds__(256) void k_init(int* gfix, __half* h1s, __half* h2s) {
    int i = blockIdx.x * 256 + threadIdx.x;
    if (i < NBUCK) gfix[i] = i * CAP;
    if (blockIdx.x == 1) {
        int t = threadIdx.x;
        if (t < 32) ((unsigned*)(h1s + (size_t)N_NODES * 64))[t] = 0u;
        else if (t < 48) ((unsigned*)(h2s + (size_t)N_NODES * 32))[t - 32] = 0u;
    }
}

// Pass A: bin packed (dlow,src) into fixed NBUCK regions of tmp.
// Shared block histogram; 8 edges/thread register-cached via int4 loads.
__global__ __launch_bounds__(256) void k_bucketA(const int* __restrict__ src,
                                                 const int* __restrict__ dst,
                                                 int* gfix, unsigned* __restrict__ tmp) {
    __shared__ int lcnt[NBUCK];
    __shared__ int lpos[NBUCK];
    int t = threadIdx.x;
    for (int b = t; b < NBUCK; b += 256) lcnt[b] = 0;
    __syncthreads();
    long e0 = (long)blockIdx.x * EPB;
    int d[8], s[8];
    #pragma unroll
    for (int h = 0; h < 2; ++h) {
        long e = e0 + h * 1024 + (long)t * 4;
        if (e + 3 < N_EDGES) {
            int4 dv = *(const int4*)&dst[e];
            int4 sv = *(const int4*)&src[e];
            d[h * 4 + 0] = dv.x; d[h * 4 + 1] = dv.y; d[h * 4 + 2] = dv.z; d[h * 4 + 3] = dv.w;
            s[h * 4 + 0] = sv.x; s[h * 4 + 1] = sv.y; s[h * 4 + 2] = sv.z; s[h * 4 + 3] = sv.w;
        } else {
            #pragma unroll
            for (int j = 0; j < 4; ++j) {
                long ee = e + j;
                d[h * 4 + j] = (ee < N_EDGES) ? dst[ee] : -1;
                s[h * 4 + j] = (ee < N_EDGES) ? src[ee] : 0;
            }
        }
    }
    #pragma unroll
    for (int k = 0; k < 8; ++k)
        if (d[k] >= 0) atomicAdd(&lcnt[d[k] >> BSHIFT], 1);
    __syncthreads();
    for (int b = t; b < NBUCK; b += 256) {
        int c = lcnt[b];
        lpos[b] = c ? atomicAdd(&gfix[b], c) : 0;
    }
    __syncthreads();
    #pragma unroll
    for (int k = 0; k < 8; ++k) {
        if (d[k] >= 0) {
            int bkt = d[k] >> BSHIFT;
            int p = atomicAdd(&lpos[bkt], 1);
            if (p < bkt * CAP + CAP)           // overflow guard (never fires)
                tmp[p] = ((unsigned)(d[k] & 255) << 17) | (unsigned)s[k];
        }
    }
}

// Pass B: one block per bucket (exclusive owner). LDS histogram of its packed
// pairs, local padded (16) exclusive scan -> rowstart/udeg/dinv; LDS-cursor
// scatter into the bucket's fixed csr region; pad tails with dummy N_NODES.
__global__ __launch_bounds__(256) void k_bucketB(const int* __restrict__ gfix,
                                                 const unsigned* __restrict__ tmp,
                                                 int* __restrict__ rowstart,
                                                 int* __restrict__ udeg,
                                                 float* __restrict__ dinv,
                                                 int* __restrict__ csr) {
    __shared__ int cnt[256];
    __shared__ int s[256];
    __shared__ int cur[256];
    __shared__ int rsl[256];
    int b  = blockIdx.x;
    int t  = threadIdx.x;
    int n0 = b << BSHIFT;
    int nn = min(256, N_NODES - n0);
    cnt[t] = 0;
    __syncthreads();
    int start = b * CAP;
    int end   = min(gfix[b], start + CAP);   // gfix[b] = start + bucket pair count
    for (int e = start + t; e < end; e += 256)
        atomicAdd(&cnt[tmp[e] >> 17], 1);
    __syncthreads();
    int c   = (t < nn) ? cnt[t] : 0;
    int pad = (c + 15) & ~15;
    s[t] = pad;
    __syncthreads();
    for (int off = 1; off < 256; off <<= 1) {
        int add = (t >= off) ? s[t - off] : 0;
        __syncthreads();
        s[t] += add;
        __syncthreads();
    }
    int rs = b * CSRCAP + s[t] - pad;        // exclusive scan within bucket
    rsl[t] = rs;
    cur[t] = rs;
    if (t < nn) {
        rowstart[n0 + t] = rs;
        udeg[n0 + t]     = c;
        dinv[n0 + t]     = rsqrtf((float)(c + 1));
    }
    __syncthreads();
    for (int e = start + t; e < end; e += 256) {
        unsigned p = tmp[e];
        int pos = atomicAdd(&cur[p >> 17], 1);
        csr[pos] = (int)(p & 0x1FFFFu);
    }
    __syncthreads();
    int pe = rsl[t] + pad;                   // cur[t] == rsl[t]+c after scatter
    for (int p = cur[t]; p < pe; ++p) csr[p] = N_NODES;
}

// h1s = fp16((x @ W1) * dinv[row])
__global__ __launch_bounds__(256) void k_gemm1(const float* __restrict__ x,
                                               const float* __restrict__ W1,
                                               const float* __restrict__ dinv,
                                               __half* __restrict__ h1s) {
    __shared__ float Ws[128 * 64];      // 32 KB
    __shared__ float xs[16][132];       // +4 pad, conflict-free
    int tid = threadIdx.x;
    for (int i = tid * 4; i < 128 * 64; i += 1024)
        *(float4*)&Ws[i] = *(const float4*)&W1[i];
    long rowBase = (long)blockIdx.x * 16;
    for (int i = tid; i < 512; i += 256) {
        int r = i >> 5, c4 = i & 31;
        *(float4*)&xs[r][c4 * 4] = *(const float4*)&x[(rowBase + r) * 128 + c4 * 4];
    }
    __syncthreads();
    int r  = tid >> 4;
    int cg = (tid & 15) * 4;
    float a0 = 0, a1 = 0, a2 = 0, a3 = 0;
    #pragma unroll
    for (int k = 0; k < 128; ++k) {
        float xv = xs[r][k];
        const float* w = &Ws[k * 64 + cg];
        a0 = fmaf(xv, w[0], a0); a1 = fmaf(xv, w[1], a1);
        a2 = fmaf(xv, w[2], a2); a3 = fmaf(xv, w[3], a3);
    }
    long row = rowBase + r;
    float dv = dinv[row];
    ushort4 pk;
    pk.x = __half_as_ushort(__float2half_rn(a0 * dv));
    pk.y = __half_as_ushort(__float2half_rn(a1 * dv));
    pk.z = __half_as_ushort(__float2half_rn(a2 * dv));
    pk.w = __half_as_ushort(__float2half_rn(a3 * dv));
    *(ushort4*)&h1s[row * 64 + cg] = pk;
}

// Fused layer-1 gather + layer-2 GEMM. Wave per node.
// lane = (pr = c>>4 in {0..3}, hc = c&15 -> channels 4hc..4hc+3).
// 16 neighbors/iter: 4 int4 csr broadcasts + 4 x 8B row loads per lane.
__global__ __launch_bounds__(256) void k_fused1(const int* __restrict__ rowstart,
                                                const int* __restrict__ udeg,
                                                const int* __restrict__ csr,
                                                const float* __restrict__ dinv,
                                                const __half* __restrict__ h1s,
                                                const float* __restrict__ b1,
                                                const float* __restrict__ W2,
                                                __half* __restrict__ h2s) {
    __shared__ float W2s[64 * 32];   // 8 KB
    __shared__ float g1row[4][72];   // per-wave row, padded
    int tid = threadIdx.x;
    for (int idx = tid * 4; idx < 64 * 32; idx += 1024)
        *(float4*)&W2s[idx] = *(const float4*)&W2[idx];
    __syncthreads();                 // covers W2s staging only
    int w = tid >> 6, c = tid & 63;
    int pr = c >> 4, hc = c & 15;
    int i = blockIdx.x * 4 + w;
    int n = udeg[i];
    int base = rowstart[i];
    float4 acc = {0.f, 0.f, 0.f, 0.f};
    if (pr == 0) {
        uint2 v = *(const uint2*)(h1s + (size_t)i * 64 + hc * 4);
        float2 a = __half22float2(*(__half2*)&v.x);
        float2 b = __half22float2(*(__half2*)&v.y);
        acc.x = a.x; acc.y = a.y; acc.z = b.x; acc.w = b.y;
    }
    for (int k = 0; k < n; k += 16) {
        int4 ia = *(const int4*)&csr[base + k];
        int4 ib = *(const int4*)&csr[base + k + 4];
        int4 ic = *(const int4*)&csr[base + k + 8];
        int4 id = *(const int4*)&csr[base + k + 12];
        int s0, s1, s2, s3;
        switch (pr) {
            case 0:  s0 = ia.x; s1 = ib.x; s2 = ic.x; s3 = id.x; break;
            case 1:  s0 = ia.y; s1 = ib.y; s2 = ic.y; s3 = id.y; break;
            case 2:  s0 = ia.z; s1 = ib.z; s2 = ic.z; s3 = id.z; break;
            default: s0 = ia.w; s1 = ib.w; s2 = ic.w; s3 = id.w; break;
        }
        uint2 v0 = *(const uint2*)(h1s + (size_t)s0 * 64 + hc * 4);
        uint2 v1 = *(const uint2*)(h1s + (size_t)s1 * 64 + hc * 4);
        uint2 v2 = *(const uint2*)(h1s + (size_t)s2 * 64 + hc * 4);
        uint2 v3 = *(const uint2*)(h1s + (size_t)s3 * 64 + hc * 4);
        float2 a0 = __half22float2(*(__half2*)&v0.x), b0 = __half22float2(*(__half2*)&v0.y);
        float2 a1 = __half22float2(*(__half2*)&v1.x), b1f = __half22float2(*(__half2*)&v1.y);
        float2 a2 = __half22float2(*(__half2*)&v2.x), b2f = __half22float2(*(__half2*)&v2.y);
        float2 a3 = __half22float2(*(__half2*)&v3.x), b3f = __half22float2(*(__half2*)&v3.y);
        acc.x += (a0.x + a1.x) + (a2.x + a3.x);
        acc.y += (a0.y + a1.y) + (a2.y + a3.y);
        acc.z += (b0.x + b1f.x) + (b2f.x + b3f.x);
        acc.w += (b0.y + b1f.y) + (b2f.y + b3f.y);
    }
    acc.x += __shfl_xor(acc.x, 16); acc.y += __shfl_xor(acc.y, 16);
    acc.z += __shfl_xor(acc.z, 16); acc.w += __shfl_xor(acc.w, 16);
    acc.x += __shfl_xor(acc.x, 32); acc.y += __shfl_xor(acc.y, 32);
    acc.z += __shfl_xor(acc.z, 32); acc.w += __shfl_xor(acc.w, 32);
    float dvi = dinv[i];
    if (pr == 0) {
        float4 bb = *(const float4*)&b1[hc * 4];
        float4 g;
        g.x = fmaxf(fmaf(dvi, acc.x, bb.x), 0.f);
        g.y = fmaxf(fmaf(dvi, acc.y, bb.y), 0.f);
        g.z = fmaxf(fmaf(dvi, acc.z, bb.z), 0.f);
        g.w = fmaxf(fmaf(dvi, acc.w, bb.w), 0.f);
        *(float4*)&g1row[w][hc * 4] = g;
    }
    // wave-private LDS RAW: compiler inserts lgkmcnt wait; no barrier needed
    int j = c & 31, hf = c >> 5;
    float dot = 0.f;
    #pragma unroll
    for (int cc = 0; cc < 32; ++cc)
        dot = fmaf(g1row[w][hf * 32 + cc], W2s[(hf * 32 + cc) * 32 + j], dot);
    dot += __shfl_xor(dot, 32);
    if (hf == 0)
        h2s[(size_t)i * 32 + j] = __float2half_rn(dot * dvi);
}

// out[i] = dinv[i]*(sum_s h2s[s] + h2s[i]) + b2 — wave per node.
// lane = (pr = c>>3 in {0..7}, hc = c&7 -> channels 4hc..4hc+3).
__global__ __launch_bounds__(256) void k_gather2(const int* __restrict__ rowstart,
                                                 const int* __restrict__ udeg,
                                                 const int* __restrict__ csr,
                                                 const float* __restrict__ dinv,
                                                 const __half* __restrict__ h2s,
                                                 const float* __restrict__ b2,
                                                 float* __restrict__ out) {
    int tid = threadIdx.x;
    int w = tid >> 6, c = tid & 63;
    int pr = c >> 3, hc = c & 7;
    int i = blockIdx.x * 4 + w;
    int n = udeg[i];
    int base = rowstart[i];
    float4 acc = {0.f, 0.f, 0.f, 0.f};
    if (pr == 0) {
        uint2 v = *(const uint2*)(h2s + (size_t)i * 32 + hc * 4);
        float2 a = __half22float2(*(__half2*)&v.x);
        float2 b = __half22float2(*(__half2*)&v.y);
        acc.x = a.x; acc.y = a.y; acc.z = b.x; acc.w = b.y;
    }
    for (int k = 0; k < n; k += 16) {
        int4 ia = *(const int4*)&csr[base + k];
        int4 ib = *(const int4*)&csr[base + k + 4];
        int4 ic = *(const int4*)&csr[base + k + 8];
        int4 id = *(const int4*)&csr[base + k + 12];
        int s0, s1;
        switch (pr) {
            case 0:  s0 = ia.x; s1 = ic.x; break;
            case 1:  s0 = ia.y; s1 = ic.y; break;
            case 2:  s0 = ia.z; s1 = ic.z; break;
            case 3:  s0 = ia.w; s1 = ic.w; break;
            case 4:  s0 = ib.x; s1 = id.x; break;
            case 5:  s0 = ib.y; s1 = id.y; break;
            case 6:  s0 = ib.z; s1 = id.z; break;
            default: s0 = ib.w; s1 = id.w; break;
        }
        uint2 v0 = *(const uint2*)(h2s + (size_t)s0 * 32 + hc * 4);
        uint2 v1 = *(const uint2*)(h2s + (size_t)s1 * 32 + hc * 4);
        float2 a0 = __half22float2(*(__half2*)&v0.x), b0 = __half22float2(*(__half2*)&v0.y);
        float2 a1 = __half22float2(*(__half2*)&v1.x), b1f = __half22float2(*(__half2*)&v1.y);
        acc.x += a0.x + a1.x; acc.y += a0.y + a1.y;
        acc.z += b0.x + b1f.x; acc.w += b0.y + b1f.y;
    }
    acc.x += __shfl_xor(acc.x, 8);  acc.y += __shfl_xor(acc.y, 8);
    acc.z += __shfl_xor(acc.z, 8);  acc.w += __shfl_xor(acc.w, 8);
    acc.x += __shfl_xor(acc.x, 16); acc.y += __shfl_xor(acc.y, 16);
    acc.z += __shfl_xor(acc.z, 16); acc.w += __shfl_xor(acc.w, 16);
    acc.x += __shfl_xor(acc.x, 32); acc.y += __shfl_xor(acc.y, 32);
    acc.z += __shfl_xor(acc.z, 32); acc.w += __shfl_xor(acc.w, 32);
    if (pr == 0) {
        float dvi = dinv[i];
        float4 bb = *(const float4*)&b2[hc * 4];
        float4 o;
        o.x = fmaf(dvi, acc.x, bb.x);
        o.y = fmaf(dvi, acc.y, bb.y);
        o.z = fmaf(dvi, acc.z, bb.z);
        o.w = fmaf(dvi, acc.w, bb.w);
        *(float4*)&out[(size_t)i * 32 + hc * 4] = o;
    }
}

extern "C" void kernel_launch(void* const* d_in, const int* in_sizes, int n_in,
                              void* d_out, int out_size, void* d_ws, size_t ws_size,
                              hipStream_t stream) {
    const float* x  = (const float*)d_in[0];
    const int*   ei = (const int*)d_in[1];     // [2][N_EDGES]: row0=src, row1=dst
    const float* W1 = (const float*)d_in[2];
    const float* b1 = (const float*)d_in[3];
    const float* W2 = (const float*)d_in[4];
    const float* b2 = (const float*)d_in[5];
    float* out = (float*)d_out;

    const int* src = ei;
    const int* dst = ei + N_EDGES;

    char* ws = (char*)d_ws;
    const size_t MB = 1u << 20;
    int*      udeg     = (int*)     (ws + 0);                    // 400 KB
    float*    dinv     = (float*)   (ws + 512 * 1024);           // 400 KB
    int*      rowstart = (int*)     (ws + 1 * MB);               // 400 KB
    int*      gfix     = (int*)     (ws + 1 * MB + 512 * 1024);  // 391 ints
    int*      csr      = (int*)     (ws + 2 * MB);               // 391*6656*4 = 10.4 MB
    unsigned* tmp      = (unsigned*)(ws + 13 * MB);              // 391*5120*4 = 8.0 MB
    __half*   h1s      = (__half*)  (ws + 22 * MB);              // (N+1)*128B = 12.8 MB
    __half*   h2s      = (__half*)  (ws + 35 * MB);              // (N+1)*64B  = 6.4 MB (ends ~41.4 MB)

    k_init   <<<2, 256, 0, stream>>>(gfix, h1s, h2s);
    k_bucketA<<<NBLKA, 256, 0, stream>>>(src, dst, gfix, tmp);
    k_bucketB<<<NBUCK, 256, 0, stream>>>(gfix, tmp, rowstart, udeg, dinv, csr);
    k_gemm1  <<<N_NODES / 16, 256, 0, stream>>>(x, W1, dinv, h1s);
    k_fused1 <<<N_NODES / 4, 256, 0, stream>>>(rowstart, udeg, csr, dinv, h1s, b1, W2, h2s);
    k_gather2<<<N_NODES / 4, 256, 0, stream>>>(rowstart, udeg, csr, dinv, h2s, b2, out);
}